// Round 9
// baseline (241.270 us; speedup 1.0000x reference)
//
#include <hip/hip_runtime.h>
#include <hip/hip_bf16.h>

#define NB 32768      // batch rows per node
#define CD 128        // input channels
#define NNODES 6
#define OUTW 1536     // 6*256 output cols
#define KW 256        // concat K per node GEMM
#define NPERSIST 512  // persistent blocks = 2/CU x 256 CU
#define NITER (NB / 16 / NPERSIST)   // 4 row-groups per block

typedef __attribute__((ext_vector_type(8))) short short8;
typedef __attribute__((ext_vector_type(4))) short s16x4;   // 'short4' is a HIP builtin
typedef __attribute__((ext_vector_type(4))) float f32x4;

// hardware f32->bf16 (RNE)
static __device__ __forceinline__ short f2bf(float f) {
    union { __bf16 b; short s; } u;
    u.b = (__bf16)f;
    return u.s;
}

static __device__ __forceinline__ short8 pack8(f32x4 a, f32x4 b) {
    short8 p;
    #pragma unroll
    for (int j = 0; j < 4; ++j) { p[j] = f2bf(a[j]); p[4 + j] = f2bf(b[j]); }
    return p;
}

static __device__ __forceinline__ s16x4 pack4(f32x4 a) {
    s16x4 p;
    #pragma unroll
    for (int j = 0; j < 4; ++j) p[j] = f2bf(a[j]);
    return p;
}

// ---- prologue: Wcat[o][k] bf16 in d_ws; k<128 -> Wl[o][k], else Wr[o][k-128]
__global__ void prep_w(const float* __restrict__ Wl, const float* __restrict__ Wr,
                       short* __restrict__ Wb) {
    const int i = (blockIdx.x * 256 + threadIdx.x) * 8;
    const int o = i >> 8;
    const int k = i & 255;
    const float* src = (k < 128) ? (Wl + o * CD + k) : (Wr + o * CD + (k - 128));
    *(short8*)(Wb + i) = pack8(*(const f32x4*)src, *(const f32x4*)(src + 4));
}

// LDS short-index, XOR swizzle (byte ^= (r&7)<<4): panel p(0..9), row r(0..15),
// k(0..127). Bijective for 8B/16B accesses; reads 2-way max. Verified R5/R8.
#define LIDX(p, r, k) ((((p) << 11) + ((r) << 7) + (k)) ^ (((r) & 7) << 3))

// panels: 0:g0 1:g1 2:g25 3:g34 4..9:x0..x5
static __device__ __forceinline__ void prep_panels(short* __restrict__ A,
                                                   int r, int c, const f32x4* xv) {
    f32x4 S01 = xv[0] + xv[1], S25 = xv[2] + xv[5], S34 = xv[3] + xv[4];
    f32x4 T = S01 + S25 + S34;
    const int k = c * 4;
    *(s16x4*)&A[LIDX(0, r, k)] = pack4((T - xv[0]) * 0.2f);
    *(s16x4*)&A[LIDX(1, r, k)] = pack4((T - xv[1]) * 0.2f);
    *(s16x4*)&A[LIDX(2, r, k)] = pack4((S01 + S34) * 0.25f);
    *(s16x4*)&A[LIDX(3, r, k)] = pack4((S01 + S25) * 0.25f);
    #pragma unroll
    for (int s = 0; s < NNODES; ++s)
        *(s16x4*)&A[LIDX(4 + s, r, k)] = pack4(xv[s]);
}

// Persistent double-buffered pipeline: 512 blocks x 4 row-groups each.
// Iter: issue next group's x loads (regs) -> compute current from LDS ->
// convert+write next into other LDS buffer (vmcnt waits here, hidden under
// compute) -> barrier. Structure/layouts validated R4/R5/R8; NT stores
// REVERTED (R8: +80 MB partial-line write traffic, +35 us).
__global__ __launch_bounds__(512, 4)
void sage_v7(const float* __restrict__ x, const short* __restrict__ Wb,
             const float* __restrict__ bias, float* __restrict__ out) {
    __shared__ __align__(16) short A[2][10 * 16 * 128];   // 2 x 40 KB

    const int t = threadIdx.x;
    // prep mapping
    const int r = t >> 5;
    const int c = t & 31;
    // compute mapping
    const int lane = t & 63;
    const int wv = t >> 6;
    const int ng = wv >> 2;        // node group 0:{0,1,2} 1:{3,4,5}
    const int strip = wv & 3;      // 64-col strip
    const int lo = lane & 15;
    const int hi = lane >> 4;
    const int paA = ng ? 3 : 0;
    const int paB = ng ? 3 : 1;
    const int pxb = 4 + ng * 3;

    f32x4 xv[NNODES];
    size_t rg = blockIdx.x;

    // prologue: load + prep group 0 into buffer 0
    {
        const float* pb = x + (rg * 16 + r) * CD + c * 4;
        #pragma unroll
        for (int s = 0; s < NNODES; ++s)
            xv[s] = *(const f32x4*)(pb + (size_t)s * (NB * CD));
        prep_panels(A[0], r, c, xv);
    }
    __syncthreads();

    #pragma unroll 1
    for (int it = 0; it < NITER; ++it) {
        const int buf = it & 1;
        const bool havenext = (it < NITER - 1);
        const size_t nrg = rg + NPERSIST;

        // (1) issue next group's global loads early (latency hides under MFMA)
        if (havenext) {
            const float* pb = x + (nrg * 16 + r) * CD + c * 4;
            #pragma unroll
            for (int s = 0; s < NNODES; ++s)
                xv[s] = *(const f32x4*)(pb + (size_t)s * (NB * CD));
        }

        // (2) compute current group from A[buf]
        const short* Ab = A[buf];
        f32x4 acc[3][4];
        #pragma unroll
        for (int n = 0; n < 3; ++n)
            #pragma unroll
            for (int i = 0; i < 4; ++i) acc[n][i] = (f32x4){0.f, 0.f, 0.f, 0.f};

        #pragma unroll
        for (int m = 0; m < 4; ++m) {
            const int kk = m * 32 + hi * 8;
            short8 fgA = *(const short8*)&Ab[LIDX(paA, lo, kk)];
            short8 fgB = *(const short8*)&Ab[LIDX(paB, lo, kk)];
            short8 fgC = *(const short8*)&Ab[LIDX(2,   lo, kk)];
            short8 fx0 = *(const short8*)&Ab[LIDX(pxb + 0, lo, kk)];
            short8 fx1 = *(const short8*)&Ab[LIDX(pxb + 1, lo, kk)];
            short8 fx2 = *(const short8*)&Ab[LIDX(pxb + 2, lo, kk)];
            #pragma unroll
            for (int i = 0; i < 4; ++i) {
                const int o = strip * 64 + i * 16 + lo;
                short8 wa = *(const short8*)&Wb[o * KW + kk];
                short8 wx = *(const short8*)&Wb[o * KW + 128 + kk];
                acc[0][i] = __builtin_amdgcn_mfma_f32_16x16x32_bf16(wa, fgA, acc[0][i], 0, 0, 0);
                acc[1][i] = __builtin_amdgcn_mfma_f32_16x16x32_bf16(wa, fgB, acc[1][i], 0, 0, 0);
                acc[2][i] = __builtin_amdgcn_mfma_f32_16x16x32_bf16(wa, fgC, acc[2][i], 0, 0, 0);
                acc[0][i] = __builtin_amdgcn_mfma_f32_16x16x32_bf16(wx, fx0, acc[0][i], 0, 0, 0);
                acc[1][i] = __builtin_amdgcn_mfma_f32_16x16x32_bf16(wx, fx1, acc[1][i], 0, 0, 0);
                acc[2][i] = __builtin_amdgcn_mfma_f32_16x16x32_bf16(wx, fx2, acc[2][i], 0, 0, 0);
            }
        }

        // epilogue: lane f32x4 = out[row][col..col+3]; bias is per-node-channel
        const size_t orow = rg * 16 + lo;
        #pragma unroll
        for (int n = 0; n < 3; ++n) {
            #pragma unroll
            for (int i = 0; i < 4; ++i) {
                const int ocol = strip * 64 + i * 16 + hi * 4;
                const int col = (ng * 3 + n) * 256 + ocol;
                f32x4 v = acc[n][i] + *(const f32x4*)&bias[ocol];
                f32x4 g;
                #pragma unroll
                for (int j = 0; j < 4; ++j) {
                    const float s = v[j] * (0.7978845608f + 0.0356774081f * v[j] * v[j]);
                    const float rr = __builtin_amdgcn_exp2f(-2.885390082f * s);
                    g[j] = v[j] * __builtin_amdgcn_rcpf(1.0f + rr);
                }
                *(f32x4*)&out[orow * OUTW + col] = g;
            }
        }

        // (3) convert + write next group into the other buffer (reads of
        // A[buf] all happened above; writes target A[buf^1] -> no race)
        if (havenext) prep_panels(A[buf ^ 1], r, c, xv);
        __syncthreads();
        rg = nrg;
    }
}

extern "C" void kernel_launch(void* const* d_in, const int* in_sizes, int n_in,
                              void* d_out, int out_size, void* d_ws, size_t ws_size,
                              hipStream_t stream) {
    const float* x  = (const float*)d_in[0];
    const float* Wl = (const float*)d_in[1];
    const float* Wr = (const float*)d_in[2];
    const float* b  = (const float*)d_in[3];
    float* out = (float*)d_out;
    short* Wb = (short*)d_ws;   // 256*256 bf16 = 128 KB

    prep_w<<<dim3(32), dim3(256), 0, stream>>>(Wl, Wr, Wb);
    sage_v7<<<dim3(NPERSIST), dim3(512), 0, stream>>>(x, Wb, b, out);
}

// Round 10
// 101.579 us; speedup vs baseline: 2.3752x; 2.3752x over previous
//
#include <hip/hip_runtime.h>
#include <hip/hip_bf16.h>

#define NB 32768      // batch rows per node
#define CD 128        // input channels
#define NNODES 6
#define OUTW 1536     // 6*256 output cols
#define KW 256        // concat K per node GEMM

typedef __attribute__((ext_vector_type(8))) short short8;
typedef __attribute__((ext_vector_type(4))) short s16x4;   // 'short4' is a HIP builtin
typedef __attribute__((ext_vector_type(4))) float f32x4;

// hardware f32->bf16 (RNE)
static __device__ __forceinline__ short f2bf(float f) {
    union { __bf16 b; short s; } u;
    u.b = (__bf16)f;
    return u.s;
}

static __device__ __forceinline__ short8 pack8(f32x4 a, f32x4 b) {
    short8 p;
    #pragma unroll
    for (int j = 0; j < 4; ++j) { p[j] = f2bf(a[j]); p[4 + j] = f2bf(b[j]); }
    return p;
}

static __device__ __forceinline__ s16x4 pack4(f32x4 a) {
    s16x4 p;
    #pragma unroll
    for (int j = 0; j < 4; ++j) p[j] = f2bf(a[j]);
    return p;
}

// ---- prologue: Wcat[o][k] bf16 in d_ws; k<128 -> Wl[o][k], else Wr[o][k-128]
__global__ void prep_w(const float* __restrict__ Wl, const float* __restrict__ Wr,
                       short* __restrict__ Wb) {
    const int i = (blockIdx.x * 256 + threadIdx.x) * 8;
    const int o = i >> 8;
    const int k = i & 255;
    const float* src = (k < 128) ? (Wl + o * CD + k) : (Wr + o * CD + (k - 128));
    *(short8*)(Wb + i) = pack8(*(const f32x4*)src, *(const f32x4*)(src + 4));
}

// LDS short-index, XOR swizzle (byte ^= (r&7)<<4): panel p(0..9), row r(0..15),
// k(0..127). Bijective for 8B/16B accesses; reads 2-way max. Verified R5/R8.
#define LIDX(p, r, k) ((((p) << 11) + ((r) << 7) + (k)) ^ (((r) & 7) << 3))

// R10 = R5 structure with 512-thread blocks. 8 waves share one 16-row LDS
// tile; wave = 32-col strip x ALL 6 nodes (acc[6][2], 48 regs) -> W read
// once per block, every W-frag feeds 6 MFMAs. launch_bounds(512,2) = 128
// VGPR cap: no spill (R9's failure), 2 blocks/CU, ~16 waves/CU (2x R5).
// No NT stores (R8: +80MB partial-line traffic), no prefetch (R9: spills).
__global__ __launch_bounds__(512, 2)
void sage_v8(const float* __restrict__ x, const short* __restrict__ Wb,
             const float* __restrict__ bias, float* __restrict__ out) {
    __shared__ __align__(16) short A[10 * 16 * 128];   // 40 KB

    const int t = threadIdx.x;
    const size_t row0 = (size_t)blockIdx.x * 16;

    // ---------- prep: thread -> (row r = t>>5, 4-channel chunk c = t&31)
    {
        const int r = t >> 5;
        const int c = t & 31;
        const float* pb = x + (row0 + r) * CD + c * 4;
        f32x4 v0 = *(const f32x4*)(pb + 0ull * (NB * CD));
        f32x4 v1 = *(const f32x4*)(pb + 1ull * (NB * CD));
        f32x4 v2 = *(const f32x4*)(pb + 2ull * (NB * CD));
        f32x4 v3 = *(const f32x4*)(pb + 3ull * (NB * CD));
        f32x4 v4 = *(const f32x4*)(pb + 4ull * (NB * CD));
        f32x4 v5 = *(const f32x4*)(pb + 5ull * (NB * CD));
        f32x4 S01 = v0 + v1, S25 = v2 + v5, S34 = v3 + v4;
        f32x4 T = S01 + S25 + S34;
        const int k = c * 4;
        *(s16x4*)&A[LIDX(0, r, k)] = pack4((T - v0) * 0.2f);      // g0
        *(s16x4*)&A[LIDX(1, r, k)] = pack4((T - v1) * 0.2f);      // g1
        *(s16x4*)&A[LIDX(2, r, k)] = pack4((S01 + S34) * 0.25f);  // g25
        *(s16x4*)&A[LIDX(3, r, k)] = pack4((S01 + S25) * 0.25f);  // g34
        *(s16x4*)&A[LIDX(4, r, k)] = pack4(v0);
        *(s16x4*)&A[LIDX(5, r, k)] = pack4(v1);
        *(s16x4*)&A[LIDX(6, r, k)] = pack4(v2);
        *(s16x4*)&A[LIDX(7, r, k)] = pack4(v3);
        *(s16x4*)&A[LIDX(8, r, k)] = pack4(v4);
        *(s16x4*)&A[LIDX(9, r, k)] = pack4(v5);
    }
    __syncthreads();

    // ---------- compute: wave wv (0..7) = 32-col strip; all 6 nodes per wave
    const int lane = t & 63;
    const int wv = t >> 6;
    const int lo = lane & 15;
    const int hi = lane >> 4;
    const int obase = wv * 32;

    f32x4 acc[NNODES][2];
    #pragma unroll
    for (int n = 0; n < NNODES; ++n)
        #pragma unroll
        for (int i = 0; i < 2; ++i) acc[n][i] = (f32x4){0.f, 0.f, 0.f, 0.f};

    #pragma unroll
    for (int m = 0; m < 4; ++m) {
        const int kk = m * 32 + hi * 8;
        short8 fg0  = *(const short8*)&A[LIDX(0, lo, kk)];
        short8 fg1  = *(const short8*)&A[LIDX(1, lo, kk)];
        short8 fg25 = *(const short8*)&A[LIDX(2, lo, kk)];
        short8 fg34 = *(const short8*)&A[LIDX(3, lo, kk)];
        short8 fx0 = *(const short8*)&A[LIDX(4, lo, kk)];
        short8 fx1 = *(const short8*)&A[LIDX(5, lo, kk)];
        short8 fx2 = *(const short8*)&A[LIDX(6, lo, kk)];
        short8 fx3 = *(const short8*)&A[LIDX(7, lo, kk)];
        short8 fx4 = *(const short8*)&A[LIDX(8, lo, kk)];
        short8 fx5 = *(const short8*)&A[LIDX(9, lo, kk)];

        #pragma unroll
        for (int i = 0; i < 2; ++i) {
            const int o = obase + i * 16 + lo;
            short8 wa = *(const short8*)&Wb[o * KW + kk];          // Wl half
            short8 wx = *(const short8*)&Wb[o * KW + 128 + kk];    // Wr half
            acc[0][i] = __builtin_amdgcn_mfma_f32_16x16x32_bf16(wa, fg0,  acc[0][i], 0, 0, 0);
            acc[1][i] = __builtin_amdgcn_mfma_f32_16x16x32_bf16(wa, fg1,  acc[1][i], 0, 0, 0);
            acc[2][i] = __builtin_amdgcn_mfma_f32_16x16x32_bf16(wa, fg25, acc[2][i], 0, 0, 0);
            acc[3][i] = __builtin_amdgcn_mfma_f32_16x16x32_bf16(wa, fg34, acc[3][i], 0, 0, 0);
            acc[4][i] = __builtin_amdgcn_mfma_f32_16x16x32_bf16(wa, fg34, acc[4][i], 0, 0, 0);
            acc[5][i] = __builtin_amdgcn_mfma_f32_16x16x32_bf16(wa, fg25, acc[5][i], 0, 0, 0);
            acc[0][i] = __builtin_amdgcn_mfma_f32_16x16x32_bf16(wx, fx0, acc[0][i], 0, 0, 0);
            acc[1][i] = __builtin_amdgcn_mfma_f32_16x16x32_bf16(wx, fx1, acc[1][i], 0, 0, 0);
            acc[2][i] = __builtin_amdgcn_mfma_f32_16x16x32_bf16(wx, fx2, acc[2][i], 0, 0, 0);
            acc[3][i] = __builtin_amdgcn_mfma_f32_16x16x32_bf16(wx, fx3, acc[3][i], 0, 0, 0);
            acc[4][i] = __builtin_amdgcn_mfma_f32_16x16x32_bf16(wx, fx4, acc[4][i], 0, 0, 0);
            acc[5][i] = __builtin_amdgcn_mfma_f32_16x16x32_bf16(wx, fx5, acc[5][i], 0, 0, 0);
        }
    }

    // ---------- epilogue: lane f32x4 = out[row0+lo][col..col+3],
    // col = n*256 + wv*32 + i*16 + hi*4; bias per-node-channel (256 elems)
    #pragma unroll
    for (int n = 0; n < NNODES; ++n) {
        #pragma unroll
        for (int i = 0; i < 2; ++i) {
            const int ocol = obase + i * 16 + hi * 4;
            f32x4 v = acc[n][i] + *(const f32x4*)&bias[ocol];
            f32x4 g;
            #pragma unroll
            for (int j = 0; j < 4; ++j) {
                const float s = v[j] * (0.7978845608f + 0.0356774081f * v[j] * v[j]);
                const float r = __builtin_amdgcn_exp2f(-2.885390082f * s);
                g[j] = v[j] * __builtin_amdgcn_rcpf(1.0f + r);
            }
            *(f32x4*)&out[(row0 + lo) * OUTW + n * 256 + ocol] = g;
        }
    }
}

extern "C" void kernel_launch(void* const* d_in, const int* in_sizes, int n_in,
                              void* d_out, int out_size, void* d_ws, size_t ws_size,
                              hipStream_t stream) {
    const float* x  = (const float*)d_in[0];
    const float* Wl = (const float*)d_in[1];
    const float* Wr = (const float*)d_in[2];
    const float* b  = (const float*)d_in[3];
    float* out = (float*)d_out;
    short* Wb = (short*)d_ws;   // 256*256 bf16 = 128 KB

    prep_w<<<dim3(32), dim3(256), 0, stream>>>(Wl, Wr, Wb);
    sage_v8<<<dim3(NB / 16), dim3(512), 0, stream>>>(x, Wb, b, out);
}

// Round 11
// 92.207 us; speedup vs baseline: 2.6166x; 1.1016x over previous
//
#include <hip/hip_runtime.h>
#include <hip/hip_bf16.h>

#define NB 32768      // batch rows per node
#define CD 128        // input channels
#define NNODES 6
#define OUTW 1536     // 6*256 output cols
#define KW 256        // concat K per node GEMM
#define GPB 8         // row-groups per persistent block
#define NBLK (NB / 16 / GPB)   // 256 blocks = 1 per CU

typedef __attribute__((ext_vector_type(8))) short short8;
typedef __attribute__((ext_vector_type(4))) short s16x4;   // 'short4' is a HIP builtin
typedef __attribute__((ext_vector_type(4))) float f32x4;

// hardware f32->bf16 (RNE)
static __device__ __forceinline__ short f2bf(float f) {
    union { __bf16 b; short s; } u;
    u.b = (__bf16)f;
    return u.s;
}

static __device__ __forceinline__ short8 pack8(f32x4 a, f32x4 b) {
    short8 p;
    #pragma unroll
    for (int j = 0; j < 4; ++j) { p[j] = f2bf(a[j]); p[4 + j] = f2bf(b[j]); }
    return p;
}

static __device__ __forceinline__ s16x4 pack4(f32x4 a) {
    s16x4 p;
    #pragma unroll
    for (int j = 0; j < 4; ++j) p[j] = f2bf(a[j]);
    return p;
}

// ---- prologue: Wcat[o][k] bf16 in d_ws; k<128 -> Wl[o][k], else Wr[o][k-128]
__global__ void prep_w(const float* __restrict__ Wl, const float* __restrict__ Wr,
                       short* __restrict__ Wb) {
    const int i = (blockIdx.x * 256 + threadIdx.x) * 8;
    const int o = i >> 8;
    const int k = i & 255;
    const float* src = (k < 128) ? (Wl + o * CD + k) : (Wr + o * CD + (k - 128));
    *(short8*)(Wb + i) = pack8(*(const f32x4*)src, *(const f32x4*)(src + 4));
}

// LDS short-index, XOR swizzle (byte ^= (r&7)<<4): panel p(0..9), row r(0..15),
// k(0..127). Bijective for 8B/16B accesses; reads 2-way max. Verified R5-R10.
#define LIDX(p, r, k) ((((p) << 11) + ((r) << 7) + (k)) ^ (((r) & 7) << 3))

// Persistent pipeline: 256 blocks (1/CU) x 8 row-groups. Next group's raw
// fp32 x is DMA'd into LDS via global_load_lds (no VGPR cost -> no R9 spill)
// while current group's MFMA+epilogue runs; __syncthreads drains vmcnt so the
// DMA is ordered for free. Convert (raw->swizzled bf16 panels) is the only
// serial-exposed phase. MFMA mapping/panels/epilogue verbatim from R10.
__global__ __launch_bounds__(512, 2)
void sage_v9(const float* __restrict__ x, const short* __restrict__ Wb,
             const float* __restrict__ bias, float* __restrict__ out) {
    __shared__ __align__(16) float raw[2][NNODES * 16 * 128];   // 2 x 48 KB, linear
    __shared__ __align__(16) short A[10 * 16 * 128];            // 40 KB panels

    const int t = threadIdx.x;
    const int r = t >> 5;          // staging/convert row 0..15
    const int c = t & 31;          // 4-float chunk 0..31
    const int lane = t & 63;
    const int wv = t >> 6;         // wave 0..7
    const int lo = lane & 15;
    const int hi = lane >> 4;
    const int obase = wv * 32;     // 32-col strip per wave (R10-validated)
    const size_t rg0 = (size_t)blockIdx.x * GPB;

    // ---- async stage of one row-group's raw x into raw[buf] (linear layout:
    // float idx = s*2048 + row*128 + chunk*4; wave-uniform LDS base
    // s*2048 + wv*256, per-lane dest = base + lane*16B matches exactly)
    auto stage = [&](int buf, size_t rg) {
        const float* gp = x + (rg * 16 + r) * CD + c * 4;
        #pragma unroll
        for (int s = 0; s < NNODES; ++s) {
            __builtin_amdgcn_global_load_lds(
                (const __attribute__((address_space(1))) void*)(gp + (size_t)s * (NB * CD)),
                (__attribute__((address_space(3))) void*)&raw[buf][s * 2048 + wv * 256],
                16, 0, 0);
        }
    };

    // ---- convert raw[buf] -> bf16 panels (g0,g1,g25,g34,x0..x5), swizzled
    auto convert = [&](int buf) {
        const float* rb = &raw[buf][0];
        const int base = r * 128 + c * 4;
        f32x4 v0 = *(const f32x4*)&rb[0 * 2048 + base];
        f32x4 v1 = *(const f32x4*)&rb[1 * 2048 + base];
        f32x4 v2 = *(const f32x4*)&rb[2 * 2048 + base];
        f32x4 v3 = *(const f32x4*)&rb[3 * 2048 + base];
        f32x4 v4 = *(const f32x4*)&rb[4 * 2048 + base];
        f32x4 v5 = *(const f32x4*)&rb[5 * 2048 + base];
        f32x4 S01 = v0 + v1, S25 = v2 + v5, S34 = v3 + v4;
        f32x4 T = S01 + S25 + S34;
        const int k = c * 4;
        *(s16x4*)&A[LIDX(0, r, k)] = pack4((T - v0) * 0.2f);      // g0
        *(s16x4*)&A[LIDX(1, r, k)] = pack4((T - v1) * 0.2f);      // g1
        *(s16x4*)&A[LIDX(2, r, k)] = pack4((S01 + S34) * 0.25f);  // g25
        *(s16x4*)&A[LIDX(3, r, k)] = pack4((S01 + S25) * 0.25f);  // g34
        *(s16x4*)&A[LIDX(4, r, k)] = pack4(v0);
        *(s16x4*)&A[LIDX(5, r, k)] = pack4(v1);
        *(s16x4*)&A[LIDX(6, r, k)] = pack4(v2);
        *(s16x4*)&A[LIDX(7, r, k)] = pack4(v3);
        *(s16x4*)&A[LIDX(8, r, k)] = pack4(v4);
        *(s16x4*)&A[LIDX(9, r, k)] = pack4(v5);
    };

    // ---- pipeline prologue: group 0
    stage(0, rg0);
    __syncthreads();               // drains vmcnt -> DMA complete
    convert(0);
    __syncthreads();

    #pragma unroll 1
    for (int it = 0; it < GPB; ++it) {
        if (it + 1 < GPB) stage((it + 1) & 1, rg0 + it + 1);   // overlap w/ MFMA

        // ---- MFMA + epilogue for group rg0+it (R10-verbatim)
        f32x4 acc[NNODES][2];
        #pragma unroll
        for (int n = 0; n < NNODES; ++n)
            #pragma unroll
            for (int i = 0; i < 2; ++i) acc[n][i] = (f32x4){0.f, 0.f, 0.f, 0.f};

        #pragma unroll
        for (int m = 0; m < 4; ++m) {
            const int kk = m * 32 + hi * 8;
            short8 fg0  = *(const short8*)&A[LIDX(0, lo, kk)];
            short8 fg1  = *(const short8*)&A[LIDX(1, lo, kk)];
            short8 fg25 = *(const short8*)&A[LIDX(2, lo, kk)];
            short8 fg34 = *(const short8*)&A[LIDX(3, lo, kk)];
            short8 fx0 = *(const short8*)&A[LIDX(4, lo, kk)];
            short8 fx1 = *(const short8*)&A[LIDX(5, lo, kk)];
            short8 fx2 = *(const short8*)&A[LIDX(6, lo, kk)];
            short8 fx3 = *(const short8*)&A[LIDX(7, lo, kk)];
            short8 fx4 = *(const short8*)&A[LIDX(8, lo, kk)];
            short8 fx5 = *(const short8*)&A[LIDX(9, lo, kk)];
            #pragma unroll
            for (int i = 0; i < 2; ++i) {
                const int o = obase + i * 16 + lo;
                short8 wa = *(const short8*)&Wb[o * KW + kk];          // Wl half
                short8 wx = *(const short8*)&Wb[o * KW + 128 + kk];    // Wr half
                acc[0][i] = __builtin_amdgcn_mfma_f32_16x16x32_bf16(wa, fg0,  acc[0][i], 0, 0, 0);
                acc[1][i] = __builtin_amdgcn_mfma_f32_16x16x32_bf16(wa, fg1,  acc[1][i], 0, 0, 0);
                acc[2][i] = __builtin_amdgcn_mfma_f32_16x16x32_bf16(wa, fg25, acc[2][i], 0, 0, 0);
                acc[3][i] = __builtin_amdgcn_mfma_f32_16x16x32_bf16(wa, fg34, acc[3][i], 0, 0, 0);
                acc[4][i] = __builtin_amdgcn_mfma_f32_16x16x32_bf16(wa, fg34, acc[4][i], 0, 0, 0);
                acc[5][i] = __builtin_amdgcn_mfma_f32_16x16x32_bf16(wa, fg25, acc[5][i], 0, 0, 0);
                acc[0][i] = __builtin_amdgcn_mfma_f32_16x16x32_bf16(wx, fx0, acc[0][i], 0, 0, 0);
                acc[1][i] = __builtin_amdgcn_mfma_f32_16x16x32_bf16(wx, fx1, acc[1][i], 0, 0, 0);
                acc[2][i] = __builtin_amdgcn_mfma_f32_16x16x32_bf16(wx, fx2, acc[2][i], 0, 0, 0);
                acc[3][i] = __builtin_amdgcn_mfma_f32_16x16x32_bf16(wx, fx3, acc[3][i], 0, 0, 0);
                acc[4][i] = __builtin_amdgcn_mfma_f32_16x16x32_bf16(wx, fx4, acc[4][i], 0, 0, 0);
                acc[5][i] = __builtin_amdgcn_mfma_f32_16x16x32_bf16(wx, fx5, acc[5][i], 0, 0, 0);
            }
        }

        const size_t orow = (rg0 + it) * 16 + lo;
        #pragma unroll
        for (int n = 0; n < NNODES; ++n) {
            #pragma unroll
            for (int i = 0; i < 2; ++i) {
                const int ocol = obase + i * 16 + hi * 4;      // within-node channel
                f32x4 v = acc[n][i] + *(const f32x4*)&bias[ocol];
                f32x4 g;
                #pragma unroll
                for (int j = 0; j < 4; ++j) {
                    const float s = v[j] * (0.7978845608f + 0.0356774081f * v[j] * v[j]);
                    const float rr = __builtin_amdgcn_exp2f(-2.885390082f * s);
                    g[j] = v[j] * __builtin_amdgcn_rcpf(1.0f + rr);
                }
                *(f32x4*)&out[orow * OUTW + n * 256 + ocol] = g;
            }
        }

        __syncthreads();           // panels free; DMA for next group drained
        if (it + 1 < GPB) {
            convert((it + 1) & 1); // raw[next] -> panels
            __syncthreads();
        }
    }
}

extern "C" void kernel_launch(void* const* d_in, const int* in_sizes, int n_in,
                              void* d_out, int out_size, void* d_ws, size_t ws_size,
                              hipStream_t stream) {
    const float* x  = (const float*)d_in[0];
    const float* Wl = (const float*)d_in[1];
    const float* Wr = (const float*)d_in[2];
    const float* b  = (const float*)d_in[3];
    float* out = (float*)d_out;
    short* Wb = (short*)d_ws;   // 256*256 bf16 = 128 KB

    prep_w<<<dim3(32), dim3(256), 0, stream>>>(Wl, Wr, Wb);
    sage_v9<<<dim3(NBLK), dim3(512), 0, stream>>>(x, Wb, b, out);
}